// Round 7
// baseline (219.368 us; speedup 1.0000x reference)
//
#include <hip/hip_runtime.h>
#include <hip/hip_bf16.h>
#include <hip/hip_fp16.h>

// Problem constants
#define B_      4
#define N_      2048
#define DIM_    128
#define HEADS_  8
#define HEAD_   128
#define INNER_  1024
#define QKV_    3072
#define EPS_    1e-5f
#define SCALE_  0.08838834764831845f   // HEAD^-0.5
// log2(10000)/64 for rope inv_freq = 2^(-i * this)
#define ROPE_C  0.20762050593046015f

typedef __attribute__((ext_vector_type(8))) short short8;   // 8 bf16 = 4 VGPRs
typedef __attribute__((ext_vector_type(4))) short short4v;  // 4 bf16 = 2 VGPRs
typedef __attribute__((ext_vector_type(4))) float f32x4;    // MFMA C/D

// Workspace (byte offsets) — R20 layout (same as R17-R19):
//  Q    [0,16M)   K [16M,32M)   Vt [32M,48M)        (bf16)
//  Ob   [48M,64M) bf16 [B][N][INNER]
//  xnb  [96M,98M) bf16 [8192][128]
//  wqb  [98M,98.75M) bf16 [3072][128]
//  wob  [99M,99.25M) bf16 [128][1024]
//  -- split path only (requires ws_size >= 165MB):
//  Opart [100M,164M) fp32 [2][512][128][128]   (s, p=qt*32+bh, row, d)
//  psb   [164M,164.5M) fp32 [2][512][128]
//
// R20 theory: occupancy limiter is TOTAL regs (arch VGPR + acc) <= 128 for
// 4 blocks/CU; VGPR_Count counter reports arch only (R18/R19 reconciliation).
// Fix: replace reg-staged K/V (kr/vr, 32 VGPRs) with global_load_lds DMA.
// LDS dest is linear (HW requirement); the XOR swizzle is applied on the
// GLOBAL SOURCE address instead (both-sides rule), so LDS contents are
// bit-identical to R19's validated layout. Reads unchanged (kidx/vidx).

__device__ __forceinline__ unsigned short f2bf(float f) {
    unsigned u = __builtin_bit_cast(unsigned, f);
    u = (u + 0x7fffu + ((u >> 16) & 1u)) >> 16;
    return (unsigned short)u;
}
__device__ __forceinline__ float bf2f(unsigned short h) {
    unsigned u = ((unsigned)h) << 16;
    return __builtin_bit_cast(float, u);
}
__device__ __forceinline__ unsigned pk2(float a, float b) {
    return (unsigned)f2bf(a) | ((unsigned)f2bf(b) << 16);
}
// packed RNE fp32x4 -> bf16x4 via v_cvt_pk_bf16_f32 (HIP API); memcpy for the
// bit move because __hip_bfloat162 is not trivially copyable (R14 lesson).
__device__ __forceinline__ short4v pack4(const float* e) {
    __hip_bfloat162 h0 = __float22bfloat162_rn(make_float2(e[0], e[1]));
    __hip_bfloat162 h1 = __float22bfloat162_rn(make_float2(e[2], e[3]));
    uint2 u;
    __builtin_memcpy(&u.x, &h0, 4);
    __builtin_memcpy(&u.y, &h1, 4);
    return __builtin_bit_cast(short4v, u);
}

// Swizzled LDS indexing (element index in shorts).
// lK: 64 rows x 16 chunks of 8 shorts. lV: 128 rows x 8 chunks of 8 shorts.
__device__ __forceinline__ int kidx(int r, int chunk) {
    return r * 128 + ((chunk ^ (r & 7)) << 3);
}
__device__ __forceinline__ int vidx(int r, int chunk) {
    return r * 64 + ((chunk ^ (r & 7)) << 3);
}

// 16B global -> LDS direct DMA. LDS dest wave-uniform base; lane l lands at
// base + l*16. Global source is per-lane.
__device__ __forceinline__ void gl16(const void* g, void* l) {
    __builtin_amdgcn_global_load_lds(
        (const __attribute__((address_space(1))) void*)g,
        (__attribute__((address_space(3))) void*)l, 16, 0, 0);
}

// ---------------------------------------------------------------------------
// K0: LayerNorm -> bf16 xnb. One wave per row, lane holds 2 elems.
// ---------------------------------------------------------------------------
__global__ __launch_bounds__(256) void k_ln(
    const float* __restrict__ x, const float* __restrict__ g,
    const float* __restrict__ be, unsigned short* __restrict__ xnb)
{
    const int w = threadIdx.x >> 6, l = threadIdx.x & 63;
    const int row = blockIdx.x * 4 + w;
    float2 v = *(const float2*)(x + (size_t)row * 128 + l * 2);
    float s = v.x + v.y, s2 = v.x * v.x + v.y * v.y;
#pragma unroll
    for (int off = 1; off < 64; off <<= 1) {
        s  += __shfl_xor(s, off);
        s2 += __shfl_xor(s2, off);
    }
    float mu = s * (1.f / 128.f);
    float var = s2 * (1.f / 128.f) - mu * mu;
    float rs = rsqrtf(var + EPS_);
    float2 gg = *(const float2*)(g + l * 2);
    float2 bb = *(const float2*)(be + l * 2);
    float ox = (v.x - mu) * rs * gg.x + bb.x;
    float oy = (v.y - mu) * rs * gg.y + bb.y;
    *(unsigned*)(xnb + (size_t)row * 128 + l * 2) = pk2(ox, oy);
}

// ---------------------------------------------------------------------------
// K0b: fp32 -> bf16 convert (8 elems/thread)
// ---------------------------------------------------------------------------
__global__ __launch_bounds__(256) void k_cvt(
    const float* __restrict__ src, unsigned short* __restrict__ dst)
{
    size_t i = ((size_t)blockIdx.x * 256 + threadIdx.x) * 8;
    float4 f0 = *(const float4*)(src + i), f1 = *(const float4*)(src + i + 4);
    uint4 u = { pk2(f0.x, f0.y), pk2(f0.z, f0.w), pk2(f1.x, f1.y), pk2(f1.z, f1.w) };
    *(uint4*)(dst + i) = u;
}

// ---------------------------------------------------------------------------
// K1: fused QKV GEMM + rope + scatter. M=128 x N=128, K=128 one-shot.
// Grid (64, 24). (R15-validated)
// ---------------------------------------------------------------------------
__global__ __launch_bounds__(256) void k_qkvf(
    const unsigned short* __restrict__ xnb, const unsigned short* __restrict__ wb,
    unsigned short* __restrict__ Q, unsigned short* __restrict__ K,
    unsigned short* __restrict__ Vt)
{
    __shared__ unsigned short lA[128 * 136];
    __shared__ unsigned short lB[128 * 136];
    const int t = threadIdx.x;
    const int wv = t >> 6, l = t & 63;
    const int lm = l & 15, quad = l >> 4;
    const int row0 = blockIdx.x * 128;
    const int by   = blockIdx.y;
    const int e0   = by * 128;

#pragma unroll
    for (int i = 0; i < 8; ++i) {
        int c = t + 256 * i;  int r = c >> 4, c8 = c & 15;
        *(uint4*)&lA[r * 136 + c8 * 8] =
            *(const uint4*)(xnb + (size_t)(row0 + r) * 128 + c8 * 8);
        *(uint4*)&lB[r * 136 + c8 * 8] =
            *(const uint4*)(wb + (size_t)(e0 + r) * 128 + c8 * 8);
    }
    __syncthreads();

    short8 af[2][4];
#pragma unroll
    for (int mt = 0; mt < 2; ++mt)
#pragma unroll
        for (int ks = 0; ks < 4; ++ks)
            af[mt][ks] = *(short8*)&lA[(wv * 32 + mt * 16 + lm) * 136 + ks * 32 + quad * 8];

    f32x4 acc[2][8];
#pragma unroll
    for (int mt = 0; mt < 2; ++mt)
#pragma unroll
        for (int ct = 0; ct < 8; ++ct) acc[mt][ct] = (f32x4){0.f, 0.f, 0.f, 0.f};
#pragma unroll
    for (int ks = 0; ks < 4; ++ks) {
#pragma unroll
        for (int ct = 0; ct < 8; ++ct) {
            short8 b = *(short8*)&lB[(ct * 16 + lm) * 136 + ks * 32 + quad * 8];
            acc[0][ct] = __builtin_amdgcn_mfma_f32_16x16x32_bf16(af[0][ks], b, acc[0][ct], 0, 0, 0);
            acc[1][ct] = __builtin_amdgcn_mfma_f32_16x16x32_bf16(af[1][ks], b, acc[1][ct], 0, 0, 0);
        }
    }
    __syncthreads();

    const int b  = row0 >> 11;           // batch
    const int n0 = row0 & (N_ - 1);      // n within batch (block-uniform)
    const int h  = by & 7;
    const int bh = b * 8 + h;

    if (by < 16) {
        // ---- Q or K: stage row-major, rope, scatter ----
#pragma unroll
        for (int mt = 0; mt < 2; ++mt)
#pragma unroll
            for (int ct = 0; ct < 8; ++ct)
#pragma unroll
                for (int r = 0; r < 4; ++r)
                    lA[(wv * 32 + mt * 16 + quad * 4 + r) * 136 + ct * 16 + lm] =
                        f2bf(acc[mt][ct][r]);
        __syncthreads();

        const int r_loc = t >> 1, half = t & 1;
        const int n = n0 + r_loc;
        unsigned short* dst = (by < 8 ? Q : K) +
            ((size_t)bh * N_ + n) * HEAD_ + half * 64;
        const bool dorope = (n != N_ - 1);
#pragma unroll
        for (int j = 0; j < 8; ++j) {
            short8 vv = *(short8*)&lA[r_loc * 136 + half * 64 + j * 8];
            if (dorope) {
                unsigned short* pv = (unsigned short*)&vv;
#pragma unroll
                for (int p = 0; p < 4; ++p) {
                    int i0 = half * 32 + j * 4 + p;
                    float invf = exp2f(-(float)i0 * ROPE_C);
                    float th = (float)n * invf;
                    float cs = __cosf(th), sn = __sinf(th);
                    float e = bf2f(pv[2 * p]), o = bf2f(pv[2 * p + 1]);
                    pv[2 * p]     = f2bf(e * cs - o * sn);
                    pv[2 * p + 1] = f2bf(o * cs + e * sn);
                }
            }
            *(short8*)(dst + j * 8) = vv;
        }
    } else {
        // ---- V: stage transposed + permuted, linear copy to Vt ----
        // local n = wv*32 + mt*16 + quad*4 + r  ->  n' = wv*32 + quad*8 + mt*4 + r
#pragma unroll
        for (int mt = 0; mt < 2; ++mt)
#pragma unroll
            for (int ct = 0; ct < 8; ++ct)
#pragma unroll
                for (int r = 0; r < 4; ++r)
                    lA[(ct * 16 + lm) * 136 + wv * 32 + quad * 8 + mt * 4 + r] =
                        f2bf(acc[mt][ct][r]);
        __syncthreads();

        const int d = t >> 1, half = t & 1;
        unsigned short* dst = Vt + ((size_t)bh * HEAD_ + d) * N_ + n0 + half * 64;
#pragma unroll
        for (int j = 0; j < 8; ++j)
            *(short8*)(dst + j * 8) = *(short8*)&lA[d * 136 + half * 64 + j * 8];
    }
}

// ---------------------------------------------------------------------------
// K3: flash attention fallback (512 blocks, full 32 jt). gload_lds staging.
// Used only when workspace is too small for the KV-split path.
// ---------------------------------------------------------------------------
__global__ __launch_bounds__(256) void k_attn(
    const unsigned short* __restrict__ Q, const unsigned short* __restrict__ K,
    const unsigned short* __restrict__ Vt, unsigned short* __restrict__ Ob)
{
    __shared__ unsigned short lK[64 * 128];
    __shared__ unsigned short lV[128 * 64];

    const int t = threadIdx.x;
    const int w = t >> 6, l = t & 63;
    const int lm = l & 15, quad = l >> 4;
    const int bid = blockIdx.x;
    const int bh = bid & 31;
    const int qt = bid >> 5;          // 0..15
    const int n0 = qt * 128;
    const unsigned short* Qb = Q  + (size_t)bh * N_ * HEAD_;
    const unsigned short* Kb = K  + (size_t)bh * N_ * HEAD_;
    const unsigned short* Vb = Vt + (size_t)bh * N_ * HEAD_;

    short8 aq[2][4];
#pragma unroll
    for (int tt = 0; tt < 2; ++tt) {
        const unsigned short* qp =
            Qb + ((size_t)(n0 + tt * 64 + w * 16 + lm)) * 128 + quad * 8;
#pragma unroll
        for (int ks = 0; ks < 4; ++ks)
            aq[tt][ks] = *(const short8*)(qp + ks * 32);
    }

    f32x4 Oa[2][8];
#pragma unroll
    for (int tt = 0; tt < 2; ++tt)
#pragma unroll
        for (int i = 0; i < 8; ++i) Oa[tt][i] = (f32x4){0.f, 0.f, 0.f, 0.f};
    float ps0 = 0.f, ps1 = 0.f;      // per-lane partials for row q = lm
    const float C1 = SCALE_ * 1.44269504f;
    const float C0 = -23.08312f;     // -16*log2(e); const shift is exact

    // Pre-swizzled per-lane global source addresses (both-sides rule):
    // LDS linear [r][x] must hold K[r][x ^ (r&7)] so kidx/vidx reads see K[r][c].
    const int rKb = w * 4 + (l >> 4);                 // K row within chunk group
    const int cK  = ((l & 15) ^ (rKb & 7));           // pre-swizzled K col16
    const int dVb = w * 8 + (l >> 3);                 // V row within chunk group
    const int cV  = ((l & 7) ^ (l >> 3));             // pre-swizzled V col8
    const unsigned short* pK = Kb + (size_t)rKb * 128 + cK * 8;
    const unsigned short* pV = Vb + (size_t)dVb * (size_t)N_ + cV * 8;

    for (int jt = 0; jt < 32; ++jt) {
        __syncthreads();                   // previous tile's reads done
#pragma unroll
        for (int i = 0; i < 4; ++i) {
            gl16(pK + (size_t)i * (16 * 128), &lK[(i * 4 + w) * 512]);
            gl16(pV + (size_t)i * (32 * (size_t)N_), &lV[(i * 4 + w) * 512]);
        }
        __syncthreads();                   // drains vmcnt(0): tile ready
        pK += 64 * 128;
        pV += 64;

        short4v pf0[4], pf1[4];
#pragma unroll
        for (int nb = 0; nb < 4; ++nb) {
            f32x4 st0 = (f32x4){0.f, 0.f, 0.f, 0.f};
            f32x4 st1 = (f32x4){0.f, 0.f, 0.f, 0.f};
#pragma unroll
            for (int ks = 0; ks < 4; ++ks) {
                short8 kf = *(short8*)&lK[kidx(nb * 16 + lm, (ks << 2) + quad)];
                st0 = __builtin_amdgcn_mfma_f32_16x16x32_bf16(kf, aq[0][ks], st0, 0, 0, 0);
                st1 = __builtin_amdgcn_mfma_f32_16x16x32_bf16(kf, aq[1][ks], st1, 0, 0, 0);
            }
            float e0[4], e1[4];
#pragma unroll
            for (int r = 0; r < 4; ++r) {
                e0[r] = exp2f(st0[r] * C1 + C0);
                e1[r] = exp2f(st1[r] * C1 + C0);
                ps0 += e0[r];  ps1 += e1[r];
            }
            pf0[nb] = pack4(e0);
            pf1[nb] = pack4(e1);
        }

#pragma unroll
        for (int c2 = 0; c2 < 2; ++c2) {
            short8 ap0 = __builtin_shufflevector(pf0[2 * c2], pf0[2 * c2 + 1],
                                                 0, 1, 2, 3, 4, 5, 6, 7);
            short8 ap1 = __builtin_shufflevector(pf1[2 * c2], pf1[2 * c2 + 1],
                                                 0, 1, 2, 3, 4, 5, 6, 7);
#pragma unroll
            for (int nb8 = 0; nb8 < 8; ++nb8) {
                short8 bv = *(short8*)&lV[vidx(nb8 * 16 + lm, (c2 << 2) + quad)];
                Oa[0][nb8] = __builtin_amdgcn_mfma_f32_16x16x32_bf16(ap0, bv, Oa[0][nb8], 0, 0, 0);
                Oa[1][nb8] = __builtin_amdgcn_mfma_f32_16x16x32_bf16(ap1, bv, Oa[1][nb8], 0, 0, 0);
            }
        }
    }

    ps0 += __shfl_xor(ps0, 16);  ps0 += __shfl_xor(ps0, 32);
    ps1 += __shfl_xor(ps1, 16);  ps1 += __shfl_xor(ps1, 32);

    const int b = bh >> 3, h = bh & 7;
#pragma unroll
    for (int tt = 0; tt < 2; ++tt)
#pragma unroll
        for (int r = 0; r < 4; ++r) {
            float lsum = __shfl(tt == 0 ? ps0 : ps1, (l & 48) | (quad * 4 + r));
            float il = 1.f / lsum;
            int n = n0 + tt * 64 + w * 16 + quad * 4 + r;
            unsigned short* op = Ob + ((size_t)b * N_ + n) * INNER_ + h * HEAD_ + lm;
#pragma unroll
            for (int nb8 = 0; nb8 < 8; ++nb8)
                op[nb8 * 16] = f2bf(Oa[tt][nb8][r] * il);
        }
}

// ---------------------------------------------------------------------------
// K3b: KV-split-2 flash attention. Grid 1024 (s = bid>>9 picks KV half).
// R20: global_load_lds staging (no kr/vr regs). Target: arch VGPR <= 64 so
// arch+acc <= 128 -> 4 blocks/CU.
// ---------------------------------------------------------------------------
__global__ __launch_bounds__(256) void k_attn2(
    const unsigned short* __restrict__ Q, const unsigned short* __restrict__ K,
    const unsigned short* __restrict__ Vt, float* __restrict__ Opart,
    float* __restrict__ psb)
{
    __shared__ unsigned short lK[64 * 128];
    __shared__ unsigned short lV[128 * 64];

    const int t = threadIdx.x;
    const int w = t >> 6, l = t & 63;
    const int lm = l & 15, quad = l >> 4;
    const int bid = blockIdx.x;
    const int s   = bid >> 9;         // KV half
    const int p   = bid & 511;        // (qt<<5)|bh
    const int bh  = bid & 31;
    const int qt  = (bid >> 5) & 15;
    const int n0  = qt * 128;
    const int jt0 = s * 16;
    const unsigned short* Qb = Q  + (size_t)bh * N_ * HEAD_;
    const unsigned short* Kb = K  + (size_t)bh * N_ * HEAD_;
    const unsigned short* Vb = Vt + (size_t)bh * N_ * HEAD_;

    short8 aq[2][4];
#pragma unroll
    for (int tt = 0; tt < 2; ++tt) {
        const unsigned short* qp =
            Qb + ((size_t)(n0 + tt * 64 + w * 16 + lm)) * 128 + quad * 8;
#pragma unroll
        for (int ks = 0; ks < 4; ++ks)
            aq[tt][ks] = *(const short8*)(qp + ks * 32);
    }

    f32x4 Oa[2][8];
#pragma unroll
    for (int tt = 0; tt < 2; ++tt)
#pragma unroll
        for (int i = 0; i < 8; ++i) Oa[tt][i] = (f32x4){0.f, 0.f, 0.f, 0.f};
    float ps0 = 0.f, ps1 = 0.f;
    const float C1 = SCALE_ * 1.44269504f;
    const float C0 = -23.08312f;

    // Pre-swizzled per-lane global source addresses (see k_attn).
    const int rKb = w * 4 + (l >> 4);
    const int cK  = ((l & 15) ^ (rKb & 7));
    const int dVb = w * 8 + (l >> 3);
    const int cV  = ((l & 7) ^ (l >> 3));
    const unsigned short* pK = Kb + (size_t)(jt0 * 64 + rKb) * 128 + cK * 8;
    const unsigned short* pV = Vb + (size_t)dVb * (size_t)N_ + jt0 * 64 + cV * 8;

    for (int jt = 0; jt < 16; ++jt) {
        __syncthreads();
#pragma unroll
        for (int i = 0; i < 4; ++i) {
            gl16(pK + (size_t)i * (16 * 128), &lK[(i * 4 + w) * 512]);
            gl16(pV + (size_t)i * (32 * (size_t)N_), &lV[(i * 4 + w) * 512]);
        }
        __syncthreads();
        pK += 64 * 128;
        pV += 64;

        short4v pf0[4], pf1[4];
#pragma unroll
        for (int nb = 0; nb < 4; ++nb) {
            f32x4 st0 = (f32x4){0.f, 0.f, 0.f, 0.f};
            f32x4 st1 = (f32x4){0.f, 0.f, 0.f, 0.f};
#pragma unroll
            for (int ks = 0; ks < 4; ++ks) {
                short8 kf = *(short8*)&lK[kidx(nb * 16 + lm, (ks << 2) + quad)];
                st0 = __builtin_amdgcn_mfma_f32_16x16x32_bf16(kf, aq[0][ks], st0, 0, 0, 0);
                st1 = __builtin_amdgcn_mfma_f32_16x16x32_bf16(kf, aq[1][ks], st1, 0, 0, 0);
            }
            float e0[4], e1[4];
#pragma unroll
            for (int r = 0; r < 4; ++r) {
                e0[r] = exp2f(st0[r] * C1 + C0);
                e1[r] = exp2f(st1[r] * C1 + C0);
                ps0 += e0[r];  ps1 += e1[r];
            }
            pf0[nb] = pack4(e0);
            pf1[nb] = pack4(e1);
        }

#pragma unroll
        for (int c2 = 0; c2 < 2; ++c2) {
            short8 ap0 = __builtin_shufflevector(pf0[2 * c2], pf0[2 * c2 + 1],
                                                 0, 1, 2, 3, 4, 5, 6, 7);
            short8 ap1 = __builtin_shufflevector(pf1[2 * c2], pf1[2 * c2 + 1],
                                                 0, 1, 2, 3, 4, 5, 6, 7);
#pragma unroll
            for (int nb8 = 0; nb8 < 8; ++nb8) {
                short8 bv = *(short8*)&lV[vidx(nb8 * 16 + lm, (c2 << 2) + quad)];
                Oa[0][nb8] = __builtin_amdgcn_mfma_f32_16x16x32_bf16(ap0, bv, Oa[0][nb8], 0, 0, 0);
                Oa[1][nb8] = __builtin_amdgcn_mfma_f32_16x16x32_bf16(ap1, bv, Oa[1][nb8], 0, 0, 0);
            }
        }
    }

    ps0 += __shfl_xor(ps0, 16);  ps0 += __shfl_xor(ps0, 32);
    ps1 += __shfl_xor(ps1, 16);  ps1 += __shfl_xor(ps1, 32);

    float* Op = Opart + ((size_t)(s * 512 + p)) * 16384;
    float* pp = psb   + ((size_t)(s * 512 + p)) * 128;
#pragma unroll
    for (int tt = 0; tt < 2; ++tt)
#pragma unroll
        for (int r = 0; r < 4; ++r) {
            float lsum = __shfl(tt == 0 ? ps0 : ps1, (l & 48) | (quad * 4 + r));
            int rowl = tt * 64 + w * 16 + quad * 4 + r;
            if (lm == 0) pp[rowl] = lsum;
#pragma unroll
            for (int nb8 = 0; nb8 < 8; ++nb8)
                Op[rowl * 128 + nb8 * 16 + lm] = Oa[tt][nb8][r];
        }
}

// ---------------------------------------------------------------------------
// K3c: combine — Ob = (O0 + O1) / (ps0 + ps1), fp32 -> bf16. BW-bound.
// ---------------------------------------------------------------------------
__global__ __launch_bounds__(256) void k_comb(
    const float* __restrict__ Opart, const float* __restrict__ psb,
    unsigned short* __restrict__ Ob)
{
    __shared__ float inv[128];
    const int p = blockIdx.x;           // (qt<<5)|bh
    const int t = threadIdx.x;
    const int bh = p & 31, qt = p >> 5;
    if (t < 128) {
        float d = psb[(size_t)p * 128 + t] + psb[(size_t)(512 + p) * 128 + t];
        inv[t] = 1.f / d;
    }
    __syncthreads();
    const float* O0 = Opart + (size_t)p * 16384;
    const float* O1 = Opart + (size_t)(512 + p) * 16384;
    const int b = bh >> 3, h = bh & 7;
#pragma unroll
    for (int i = 0; i < 16; ++i) {
        int flat = i * 256 + t;          // 0..4095, 4 d per thread
        int row = flat >> 5, dq = (flat & 31) * 4;
        float4 a = *(const float4*)(O0 + row * 128 + dq);
        float4 c = *(const float4*)(O1 + row * 128 + dq);
        float iv = inv[row];
        float e[4] = { (a.x + c.x) * iv, (a.y + c.y) * iv,
                       (a.z + c.z) * iv, (a.w + c.w) * iv };
        short4v o = pack4(e);
        int n = qt * 128 + row;
        *(short4v*)(Ob + ((size_t)b * N_ + n) * INNER_ + h * HEAD_ + dq) = o;
    }
}

// ---------------------------------------------------------------------------
// K4: output projection, bf16 MFMA. out[8192,128] = Ob @ wob^T + b_out.
// ---------------------------------------------------------------------------
__global__ __launch_bounds__(256) void k_proj(
    const unsigned short* __restrict__ Ob, const unsigned short* __restrict__ wob,
    const float* __restrict__ bias, float* __restrict__ out)
{
    __shared__ unsigned short lA[64 * 136];
    __shared__ unsigned short lB[64 * 136];
    float* lCf = (float*)lA;
    const int t = threadIdx.x;
    const int wv = t >> 6, l = t & 63;
    const int lm = l & 15, quad = l >> 4;
    const int row0 = blockIdx.x * 64;
    const int e0   = blockIdx.y * 64;

    f32x4 acc[4];
#pragma unroll
    for (int ct = 0; ct < 4; ++ct) acc[ct] = (f32x4){0.f, 0.f, 0.f, 0.f};

    for (int kt = 0; kt < 8; ++kt) {
        __syncthreads();
#pragma unroll
        for (int i = 0; i < 4; ++i) {
            int c = t + 256 * i;  int r = c >> 4, c8 = c & 15;
            *(uint4*)&lA[r * 136 + c8 * 8] =
                *(const uint4*)(Ob + (size_t)(row0 + r) * 1024 + kt * 128 + c8 * 8);
            *(uint4*)&lB[r * 136 + c8 * 8] =
                *(const uint4*)(wob + (size_t)(e0 + r) * 1024 + kt * 128 + c8 * 8);
        }
        __syncthreads();
        short8 a_[4];
#pragma unroll
        for (int ks = 0; ks < 4; ++ks)
            a_[ks] = *(short8*)&lA[(wv * 16 + lm) * 136 + ks * 32 + quad * 8];
#pragma unroll
        for (int ks = 0; ks < 4; ++ks)
#pragma unroll
            for (int ct = 0; ct < 4; ++ct) {
                short8 b = *(short8*)&lB[(ct * 16 + lm) * 136 + ks * 32 + quad * 8];
                acc[ct] = __builtin_amdgcn_mfma_f32_16x16x32_bf16(a_[ks], b, acc[ct], 0, 0, 0);
            }
    }
    __syncthreads();
#pragma unroll
    for (int ct = 0; ct < 4; ++ct)
#pragma unroll
        for (int r = 0; r < 4; ++r)
            lCf[(wv * 16 + quad * 4 + r) * 68 + ct * 16 + lm] = acc[ct][r];
    __syncthreads();
#pragma unroll
    for (int i = 0; i < 4; ++i) {
        int c = t + 256 * i;  int r = c >> 4, c4 = c & 15;
        float4 v = *(float4*)&lCf[r * 68 + c4 * 4];
        float4 b4 = *(const float4*)(bias + e0 + c4 * 4);
        v.x += b4.x; v.y += b4.y; v.z += b4.z; v.w += b4.w;
        *(float4*)(out + (size_t)(row0 + r) * 128 + e0 + c4 * 4) = v;
    }
}

// ---------------------------------------------------------------------------
extern "C" void kernel_launch(void* const* d_in, const int* in_sizes, int n_in,
                              void* d_out, int out_size, void* d_ws, size_t ws_size,
                              hipStream_t stream) {
    const float* x      = (const float*)d_in[0];
    const float* gamma  = (const float*)d_in[1];
    const float* beta   = (const float*)d_in[2];
    const float* w_qkv  = (const float*)d_in[3];
    const float* w_out  = (const float*)d_in[4];
    const float* b_out  = (const float*)d_in[5];
    float* out = (float*)d_out;
    char* wsb = (char*)d_ws;
    unsigned short* Q    = (unsigned short*)(wsb);
    unsigned short* K    = (unsigned short*)(wsb + (16ull << 20));
    unsigned short* Vt   = (unsigned short*)(wsb + (32ull << 20));
    unsigned short* Ob   = (unsigned short*)(wsb + (48ull << 20));
    unsigned short* xnb  = (unsigned short*)(wsb + (96ull << 20));
    unsigned short* wqb  = (unsigned short*)(wsb + (98ull << 20));
    unsigned short* wob  = (unsigned short*)(wsb + (99ull << 20));

    k_ln       <<<dim3(2048),    256, 0, stream>>>(x, gamma, beta, xnb);
    k_cvt      <<<dim3(192),     256, 0, stream>>>(w_qkv, wqb);   // 3072*128
    k_cvt      <<<dim3(64),      256, 0, stream>>>(w_out, wob);   // 128*1024
    k_qkvf     <<<dim3(64, 24),  256, 0, stream>>>(xnb, wqb, Q, K, Vt);

    if (ws_size >= (165ull << 20)) {
        // KV-split path: more blocks/CU in attention + BW-bound combine.
        float* Opart = (float*)(wsb + (100ull << 20));
        float* psb   = (float*)(wsb + (164ull << 20));
        k_attn2 <<<dim3(1024), 256, 0, stream>>>(Q, K, Vt, Opart, psb);
        k_comb  <<<dim3(512),  256, 0, stream>>>(Opart, psb, Ob);
    } else {
        k_attn  <<<dim3(512),  256, 0, stream>>>(Q, K, Vt, Ob);
    }
    k_proj     <<<dim3(128, 2),  256, 0, stream>>>(Ob, wob, b_out, out);
}

// Round 8
// 199.306 us; speedup vs baseline: 1.1007x; 1.1007x over previous
//
#include <hip/hip_runtime.h>
#include <hip/hip_bf16.h>
#include <hip/hip_fp16.h>

// Problem constants
#define B_      4
#define N_      2048
#define DIM_    128
#define HEADS_  8
#define HEAD_   128
#define INNER_  1024
#define QKV_    3072
#define EPS_    1e-5f
#define SCALE_  0.08838834764831845f   // HEAD^-0.5
// log2(10000)/64 for rope inv_freq = 2^(-i * this)
#define ROPE_C  0.20762050593046015f

typedef __attribute__((ext_vector_type(8))) short short8;   // 8 bf16 = 4 VGPRs
typedef __attribute__((ext_vector_type(4))) short short4v;  // 4 bf16 = 2 VGPRs
typedef __attribute__((ext_vector_type(4))) float f32x4;    // MFMA C/D

// Workspace (byte offsets) — R21 layout (split path removed):
//  Q    [0,16M)   K [16M,32M)   Vt [32M,48M)        (bf16)
//  Ob   [48M,64M) bf16 [B][N][INNER]
//  xnb  [96M,98M) bf16 [8192][128]
//  wqb  [98M,98.75M) bf16 [3072][128]
//  wob  [99M,99.25M) bf16 [128][1024]
//
// R21 design notes (from R15-R20 counters):
//  - 2 blocks/CU is the fixed operating point: total regs (arch ~112 + 64
//    acc) => 2 waves/SIMD regardless of LDS. KV-split/occupancy attacks are
//    dead ends (R17-R20). Optimize the schedule at 2 blocks/CU instead.
//  - Single-barrier double-buffered K/V staging: prefetch tile jt+1 via
//    global_load_lds BEFORE computing tile jt; the one __syncthreads per jt
//    drains vmcnt (prefetch complete) AND synchronizes buffer reads. Staging
//    fully hides under MFMA+exp.
//  - 2x32KB unpadded swizzled LDS = 64KB/block -> 2 blocks/CU fits the pool
//    (R18: 3.3 blocks avg at 32KB proves pool >= 128KB).
//  - gl16 staging + pre-swizzled global source (both-sides rule) validated
//    bit-exact in R20.

__device__ __forceinline__ unsigned short f2bf(float f) {
    unsigned u = __builtin_bit_cast(unsigned, f);
    u = (u + 0x7fffu + ((u >> 16) & 1u)) >> 16;
    return (unsigned short)u;
}
__device__ __forceinline__ float bf2f(unsigned short h) {
    unsigned u = ((unsigned)h) << 16;
    return __builtin_bit_cast(float, u);
}
__device__ __forceinline__ unsigned pk2(float a, float b) {
    return (unsigned)f2bf(a) | ((unsigned)f2bf(b) << 16);
}
// packed RNE fp32x4 -> bf16x4 via v_cvt_pk_bf16_f32 (HIP API); memcpy for the
// bit move because __hip_bfloat162 is not trivially copyable (R14 lesson).
__device__ __forceinline__ short4v pack4(const float* e) {
    __hip_bfloat162 h0 = __float22bfloat162_rn(make_float2(e[0], e[1]));
    __hip_bfloat162 h1 = __float22bfloat162_rn(make_float2(e[2], e[3]));
    uint2 u;
    __builtin_memcpy(&u.x, &h0, 4);
    __builtin_memcpy(&u.y, &h1, 4);
    return __builtin_bit_cast(short4v, u);
}

// Swizzled LDS indexing (element index in shorts).
// lK: 64 rows x 16 chunks of 8 shorts. lV: 128 rows x 8 chunks of 8 shorts.
__device__ __forceinline__ int kidx(int r, int chunk) {
    return r * 128 + ((chunk ^ (r & 7)) << 3);
}
__device__ __forceinline__ int vidx(int r, int chunk) {
    return r * 64 + ((chunk ^ (r & 7)) << 3);
}

// 16B global -> LDS direct DMA. LDS dest wave-uniform base; lane l lands at
// base + l*16. Global source is per-lane.
__device__ __forceinline__ void gl16(const void* g, void* l) {
    __builtin_amdgcn_global_load_lds(
        (const __attribute__((address_space(1))) void*)g,
        (__attribute__((address_space(3))) void*)l, 16, 0, 0);
}

// ---------------------------------------------------------------------------
// K0: LayerNorm -> bf16 xnb. One wave per row, lane holds 2 elems.
// ---------------------------------------------------------------------------
__global__ __launch_bounds__(256) void k_ln(
    const float* __restrict__ x, const float* __restrict__ g,
    const float* __restrict__ be, unsigned short* __restrict__ xnb)
{
    const int w = threadIdx.x >> 6, l = threadIdx.x & 63;
    const int row = blockIdx.x * 4 + w;
    float2 v = *(const float2*)(x + (size_t)row * 128 + l * 2);
    float s = v.x + v.y, s2 = v.x * v.x + v.y * v.y;
#pragma unroll
    for (int off = 1; off < 64; off <<= 1) {
        s  += __shfl_xor(s, off);
        s2 += __shfl_xor(s2, off);
    }
    float mu = s * (1.f / 128.f);
    float var = s2 * (1.f / 128.f) - mu * mu;
    float rs = rsqrtf(var + EPS_);
    float2 gg = *(const float2*)(g + l * 2);
    float2 bb = *(const float2*)(be + l * 2);
    float ox = (v.x - mu) * rs * gg.x + bb.x;
    float oy = (v.y - mu) * rs * gg.y + bb.y;
    *(unsigned*)(xnb + (size_t)row * 128 + l * 2) = pk2(ox, oy);
}

// ---------------------------------------------------------------------------
// K0b: fp32 -> bf16 convert (8 elems/thread)
// ---------------------------------------------------------------------------
__global__ __launch_bounds__(256) void k_cvt(
    const float* __restrict__ src, unsigned short* __restrict__ dst)
{
    size_t i = ((size_t)blockIdx.x * 256 + threadIdx.x) * 8;
    float4 f0 = *(const float4*)(src + i), f1 = *(const float4*)(src + i + 4);
    uint4 u = { pk2(f0.x, f0.y), pk2(f0.z, f0.w), pk2(f1.x, f1.y), pk2(f1.z, f1.w) };
    *(uint4*)(dst + i) = u;
}

// ---------------------------------------------------------------------------
// K1: fused QKV GEMM + rope + scatter. M=128 x N=128, K=128 one-shot.
// Grid (64, 24). (R15-validated)
// ---------------------------------------------------------------------------
__global__ __launch_bounds__(256) void k_qkvf(
    const unsigned short* __restrict__ xnb, const unsigned short* __restrict__ wb,
    unsigned short* __restrict__ Q, unsigned short* __restrict__ K,
    unsigned short* __restrict__ Vt)
{
    __shared__ unsigned short lA[128 * 136];
    __shared__ unsigned short lB[128 * 136];
    const int t = threadIdx.x;
    const int wv = t >> 6, l = t & 63;
    const int lm = l & 15, quad = l >> 4;
    const int row0 = blockIdx.x * 128;
    const int by   = blockIdx.y;
    const int e0   = by * 128;

#pragma unroll
    for (int i = 0; i < 8; ++i) {
        int c = t + 256 * i;  int r = c >> 4, c8 = c & 15;
        *(uint4*)&lA[r * 136 + c8 * 8] =
            *(const uint4*)(xnb + (size_t)(row0 + r) * 128 + c8 * 8);
        *(uint4*)&lB[r * 136 + c8 * 8] =
            *(const uint4*)(wb + (size_t)(e0 + r) * 128 + c8 * 8);
    }
    __syncthreads();

    short8 af[2][4];
#pragma unroll
    for (int mt = 0; mt < 2; ++mt)
#pragma unroll
        for (int ks = 0; ks < 4; ++ks)
            af[mt][ks] = *(short8*)&lA[(wv * 32 + mt * 16 + lm) * 136 + ks * 32 + quad * 8];

    f32x4 acc[2][8];
#pragma unroll
    for (int mt = 0; mt < 2; ++mt)
#pragma unroll
        for (int ct = 0; ct < 8; ++ct) acc[mt][ct] = (f32x4){0.f, 0.f, 0.f, 0.f};
#pragma unroll
    for (int ks = 0; ks < 4; ++ks) {
#pragma unroll
        for (int ct = 0; ct < 8; ++ct) {
            short8 b = *(short8*)&lB[(ct * 16 + lm) * 136 + ks * 32 + quad * 8];
            acc[0][ct] = __builtin_amdgcn_mfma_f32_16x16x32_bf16(af[0][ks], b, acc[0][ct], 0, 0, 0);
            acc[1][ct] = __builtin_amdgcn_mfma_f32_16x16x32_bf16(af[1][ks], b, acc[1][ct], 0, 0, 0);
        }
    }
    __syncthreads();

    const int b  = row0 >> 11;           // batch
    const int n0 = row0 & (N_ - 1);      // n within batch (block-uniform)
    const int h  = by & 7;
    const int bh = b * 8 + h;

    if (by < 16) {
        // ---- Q or K: stage row-major, rope, scatter ----
#pragma unroll
        for (int mt = 0; mt < 2; ++mt)
#pragma unroll
            for (int ct = 0; ct < 8; ++ct)
#pragma unroll
                for (int r = 0; r < 4; ++r)
                    lA[(wv * 32 + mt * 16 + quad * 4 + r) * 136 + ct * 16 + lm] =
                        f2bf(acc[mt][ct][r]);
        __syncthreads();

        const int r_loc = t >> 1, half = t & 1;
        const int n = n0 + r_loc;
        unsigned short* dst = (by < 8 ? Q : K) +
            ((size_t)bh * N_ + n) * HEAD_ + half * 64;
        const bool dorope = (n != N_ - 1);
#pragma unroll
        for (int j = 0; j < 8; ++j) {
            short8 vv = *(short8*)&lA[r_loc * 136 + half * 64 + j * 8];
            if (dorope) {
                unsigned short* pv = (unsigned short*)&vv;
#pragma unroll
                for (int p = 0; p < 4; ++p) {
                    int i0 = half * 32 + j * 4 + p;
                    float invf = exp2f(-(float)i0 * ROPE_C);
                    float th = (float)n * invf;
                    float cs = __cosf(th), sn = __sinf(th);
                    float e = bf2f(pv[2 * p]), o = bf2f(pv[2 * p + 1]);
                    pv[2 * p]     = f2bf(e * cs - o * sn);
                    pv[2 * p + 1] = f2bf(o * cs + e * sn);
                }
            }
            *(short8*)(dst + j * 8) = vv;
        }
    } else {
        // ---- V: stage transposed + permuted, linear copy to Vt ----
        // local n = wv*32 + mt*16 + quad*4 + r  ->  n' = wv*32 + quad*8 + mt*4 + r
#pragma unroll
        for (int mt = 0; mt < 2; ++mt)
#pragma unroll
            for (int ct = 0; ct < 8; ++ct)
#pragma unroll
                for (int r = 0; r < 4; ++r)
                    lA[(ct * 16 + lm) * 136 + wv * 32 + quad * 8 + mt * 4 + r] =
                        f2bf(acc[mt][ct][r]);
        __syncthreads();

        const int d = t >> 1, half = t & 1;
        unsigned short* dst = Vt + ((size_t)bh * HEAD_ + d) * N_ + n0 + half * 64;
#pragma unroll
        for (int j = 0; j < 8; ++j)
            *(short8*)(dst + j * 8) = *(short8*)&lA[d * 136 + half * 64 + j * 8];
    }
}

// ---------------------------------------------------------------------------
// K3: flash attention, R21: single-barrier double-buffered gl16 staging.
// Grid 512 (bh x qt). 2x32KB swizzled LDS. Per jt: issue prefetch of tile
// jt+1 into buf[cur^1], compute tile jt from buf[cur], ONE barrier (drains
// prefetch vmcnt + syncs reads). Staging hides under MFMA+exp.
// ---------------------------------------------------------------------------
__global__ __launch_bounds__(256) void k_attn(
    const unsigned short* __restrict__ Q, const unsigned short* __restrict__ K,
    const unsigned short* __restrict__ Vt, unsigned short* __restrict__ Ob)
{
    __shared__ unsigned short lK[2][64 * 128];
    __shared__ unsigned short lV[2][128 * 64];

    const int t = threadIdx.x;
    const int w = t >> 6, l = t & 63;
    const int lm = l & 15, quad = l >> 4;
    const int bid = blockIdx.x;
    const int bh = bid & 31;
    const int qt = bid >> 5;          // 0..15
    const int n0 = qt * 128;
    const unsigned short* Qb = Q  + (size_t)bh * N_ * HEAD_;
    const unsigned short* Kb = K  + (size_t)bh * N_ * HEAD_;
    const unsigned short* Vb = Vt + (size_t)bh * N_ * HEAD_;

    short8 aq[2][4];
#pragma unroll
    for (int tt = 0; tt < 2; ++tt) {
        const unsigned short* qp =
            Qb + ((size_t)(n0 + tt * 64 + w * 16 + lm)) * 128 + quad * 8;
#pragma unroll
        for (int ks = 0; ks < 4; ++ks)
            aq[tt][ks] = *(const short8*)(qp + ks * 32);
    }

    f32x4 Oa[2][8];
#pragma unroll
    for (int tt = 0; tt < 2; ++tt)
#pragma unroll
        for (int i = 0; i < 8; ++i) Oa[tt][i] = (f32x4){0.f, 0.f, 0.f, 0.f};
    float ps0 = 0.f, ps1 = 0.f;      // per-lane partials for row q = lm
    const float C1 = SCALE_ * 1.44269504f;
    const float C0 = -23.08312f;     // -16*log2(e); const shift is exact

    // Pre-swizzled per-lane global source addresses (both-sides rule,
    // R20-validated): LDS linear [r][x] holds K[r][x ^ (r&7)].
    const int rKb = w * 4 + (l >> 4);
    const int cK  = ((l & 15) ^ (rKb & 7));
    const int dVb = w * 8 + (l >> 3);
    const int cV  = ((l & 7) ^ (l >> 3));
    const unsigned short* pK = Kb + (size_t)rKb * 128 + cK * 8;
    const unsigned short* pV = Vb + (size_t)dVb * (size_t)N_ + cV * 8;

    // Prologue: stage tile 0 into buf 0; barrier drains vmcnt -> ready.
#pragma unroll
    for (int i = 0; i < 4; ++i) {
        gl16(pK + (size_t)i * (16 * 128), &lK[0][(i * 4 + w) * 512]);
        gl16(pV + (size_t)i * (32 * (size_t)N_), &lV[0][(i * 4 + w) * 512]);
    }
    __syncthreads();
    const unsigned short* pKn = pK + 64 * 128;   // next tile (jt+1)
    const unsigned short* pVn = pV + 64;

    for (int jt = 0; jt < 32; ++jt) {
        const int cur = jt & 1;
        if (jt < 31) {
            // issue prefetch of tile jt+1 into the other buffer; in flight
            // across the compute below, drained by the barrier at loop end.
            unsigned short* dK = &lK[cur ^ 1][0];
            unsigned short* dV = &lV[cur ^ 1][0];
#pragma unroll
            for (int i = 0; i < 4; ++i) {
                gl16(pKn + (size_t)i * (16 * 128), dK + (i * 4 + w) * 512);
                gl16(pVn + (size_t)i * (32 * (size_t)N_), dV + (i * 4 + w) * 512);
            }
            pKn += 64 * 128;
            pVn += 64;
        }
        const unsigned short* lKc = &lK[cur][0];
        const unsigned short* lVc = &lV[cur][0];

        short4v pf0[4], pf1[4];
#pragma unroll
        for (int nb = 0; nb < 4; ++nb) {
            f32x4 st0 = (f32x4){0.f, 0.f, 0.f, 0.f};
            f32x4 st1 = (f32x4){0.f, 0.f, 0.f, 0.f};
#pragma unroll
            for (int ks = 0; ks < 4; ++ks) {
                short8 kf = *(short8*)&lKc[kidx(nb * 16 + lm, (ks << 2) + quad)];
                st0 = __builtin_amdgcn_mfma_f32_16x16x32_bf16(kf, aq[0][ks], st0, 0, 0, 0);
                st1 = __builtin_amdgcn_mfma_f32_16x16x32_bf16(kf, aq[1][ks], st1, 0, 0, 0);
            }
            float e0[4], e1[4];
#pragma unroll
            for (int r = 0; r < 4; ++r) {
                e0[r] = exp2f(st0[r] * C1 + C0);
                e1[r] = exp2f(st1[r] * C1 + C0);
                ps0 += e0[r];  ps1 += e1[r];
            }
            pf0[nb] = pack4(e0);
            pf1[nb] = pack4(e1);
        }

#pragma unroll
        for (int c2 = 0; c2 < 2; ++c2) {
            short8 ap0 = __builtin_shufflevector(pf0[2 * c2], pf0[2 * c2 + 1],
                                                 0, 1, 2, 3, 4, 5, 6, 7);
            short8 ap1 = __builtin_shufflevector(pf1[2 * c2], pf1[2 * c2 + 1],
                                                 0, 1, 2, 3, 4, 5, 6, 7);
#pragma unroll
            for (int nb8 = 0; nb8 < 8; ++nb8) {
                short8 bv = *(short8*)&lVc[vidx(nb8 * 16 + lm, (c2 << 2) + quad)];
                Oa[0][nb8] = __builtin_amdgcn_mfma_f32_16x16x32_bf16(ap0, bv, Oa[0][nb8], 0, 0, 0);
                Oa[1][nb8] = __builtin_amdgcn_mfma_f32_16x16x32_bf16(ap1, bv, Oa[1][nb8], 0, 0, 0);
            }
        }
        __syncthreads();   // drains prefetch vmcnt + syncs buffer reads
    }

    ps0 += __shfl_xor(ps0, 16);  ps0 += __shfl_xor(ps0, 32);
    ps1 += __shfl_xor(ps1, 16);  ps1 += __shfl_xor(ps1, 32);

    const int b = bh >> 3, h = bh & 7;
#pragma unroll
    for (int tt = 0; tt < 2; ++tt)
#pragma unroll
        for (int r = 0; r < 4; ++r) {
            float lsum = __shfl(tt == 0 ? ps0 : ps1, (l & 48) | (quad * 4 + r));
            float il = 1.f / lsum;
            int n = n0 + tt * 64 + w * 16 + quad * 4 + r;
            unsigned short* op = Ob + ((size_t)b * N_ + n) * INNER_ + h * HEAD_ + lm;
#pragma unroll
            for (int nb8 = 0; nb8 < 8; ++nb8)
                op[nb8 * 16] = f2bf(Oa[tt][nb8][r] * il);
        }
}

// ---------------------------------------------------------------------------
// K4: output projection, bf16 MFMA. out[8192,128] = Ob @ wob^T + b_out.
// ---------------------------------------------------------------------------
__global__ __launch_bounds__(256) void k_proj(
    const unsigned short* __restrict__ Ob, const unsigned short* __restrict__ wob,
    const float* __restrict__ bias, float* __restrict__ out)
{
    __shared__ unsigned short lA[64 * 136];
    __shared__ unsigned short lB[64 * 136];
    float* lCf = (float*)lA;
    const int t = threadIdx.x;
    const int wv = t >> 6, l = t & 63;
    const int lm = l & 15, quad = l >> 4;
    const int row0 = blockIdx.x * 64;
    const int e0   = blockIdx.y * 64;

    f32x4 acc[4];
#pragma unroll
    for (int ct = 0; ct < 4; ++ct) acc[ct] = (f32x4){0.f, 0.f, 0.f, 0.f};

    for (int kt = 0; kt < 8; ++kt) {
        __syncthreads();
#pragma unroll
        for (int i = 0; i < 4; ++i) {
            int c = t + 256 * i;  int r = c >> 4, c8 = c & 15;
            *(uint4*)&lA[r * 136 + c8 * 8] =
                *(const uint4*)(Ob + (size_t)(row0 + r) * 1024 + kt * 128 + c8 * 8);
            *(uint4*)&lB[r * 136 + c8 * 8] =
                *(const uint4*)(wob + (size_t)(e0 + r) * 1024 + kt * 128 + c8 * 8);
        }
        __syncthreads();
        short8 a_[4];
#pragma unroll
        for (int ks = 0; ks < 4; ++ks)
            a_[ks] = *(short8*)&lA[(wv * 16 + lm) * 136 + ks * 32 + quad * 8];
#pragma unroll
        for (int ks = 0; ks < 4; ++ks)
#pragma unroll
            for (int ct = 0; ct < 4; ++ct) {
                short8 b = *(short8*)&lB[(ct * 16 + lm) * 136 + ks * 32 + quad * 8];
                acc[ct] = __builtin_amdgcn_mfma_f32_16x16x32_bf16(a_[ks], b, acc[ct], 0, 0, 0);
            }
    }
    __syncthreads();
#pragma unroll
    for (int ct = 0; ct < 4; ++ct)
#pragma unroll
        for (int r = 0; r < 4; ++r)
            lCf[(wv * 16 + quad * 4 + r) * 68 + ct * 16 + lm] = acc[ct][r];
    __syncthreads();
#pragma unroll
    for (int i = 0; i < 4; ++i) {
        int c = t + 256 * i;  int r = c >> 4, c4 = c & 15;
        float4 v = *(float4*)&lCf[r * 68 + c4 * 4];
        float4 b4 = *(const float4*)(bias + e0 + c4 * 4);
        v.x += b4.x; v.y += b4.y; v.z += b4.z; v.w += b4.w;
        *(float4*)(out + (size_t)(row0 + r) * 128 + e0 + c4 * 4) = v;
    }
}

// ---------------------------------------------------------------------------
extern "C" void kernel_launch(void* const* d_in, const int* in_sizes, int n_in,
                              void* d_out, int out_size, void* d_ws, size_t ws_size,
                              hipStream_t stream) {
    const float* x      = (const float*)d_in[0];
    const float* gamma  = (const float*)d_in[1];
    const float* beta   = (const float*)d_in[2];
    const float* w_qkv  = (const float*)d_in[3];
    const float* w_out  = (const float*)d_in[4];
    const float* b_out  = (const float*)d_in[5];
    float* out = (float*)d_out;
    char* wsb = (char*)d_ws;
    unsigned short* Q    = (unsigned short*)(wsb);
    unsigned short* K    = (unsigned short*)(wsb + (16ull << 20));
    unsigned short* Vt   = (unsigned short*)(wsb + (32ull << 20));
    unsigned short* Ob   = (unsigned short*)(wsb + (48ull << 20));
    unsigned short* xnb  = (unsigned short*)(wsb + (96ull << 20));
    unsigned short* wqb  = (unsigned short*)(wsb + (98ull << 20));
    unsigned short* wob  = (unsigned short*)(wsb + (99ull << 20));

    k_ln       <<<dim3(2048),    256, 0, stream>>>(x, gamma, beta, xnb);
    k_cvt      <<<dim3(192),     256, 0, stream>>>(w_qkv, wqb);   // 3072*128
    k_cvt      <<<dim3(64),      256, 0, stream>>>(w_out, wob);   // 128*1024
    k_qkvf     <<<dim3(64, 24),  256, 0, stream>>>(xnb, wqb, Q, K, Vt);
    k_attn     <<<dim3(512),     256, 0, stream>>>(Q, K, Vt, Ob);
    k_proj     <<<dim3(128, 2),  256, 0, stream>>>(Ob, wob, b_out, out);
}

// Round 9
// 189.804 us; speedup vs baseline: 1.1558x; 1.0501x over previous
//
#include <hip/hip_runtime.h>
#include <hip/hip_bf16.h>
#include <hip/hip_fp16.h>

// Problem constants
#define B_      4
#define N_      2048
#define DIM_    128
#define HEADS_  8
#define HEAD_   128
#define INNER_  1024
#define QKV_    3072
#define EPS_    1e-5f
#define SCALE_  0.08838834764831845f   // HEAD^-0.5
// log2(10000)/64 for rope inv_freq = 2^(-i * this)
#define ROPE_C  0.20762050593046015f

typedef __attribute__((ext_vector_type(8))) short short8;   // 8 bf16 = 4 VGPRs
typedef __attribute__((ext_vector_type(4))) short short4v;  // 4 bf16 = 2 VGPRs
typedef __attribute__((ext_vector_type(4))) float f32x4;    // MFMA C/D

// Workspace (byte offsets):
//  Q    [0,16M)   K [16M,32M)   Vt [32M,48M)        (bf16)
//  Ob   [48M,64M) bf16 [B][N][INNER]
//  xnb  [96M,98M) bf16 [8192][128]
//  wqb  [98M,98.75M) bf16 [3072][128]
//  wob  [99M,99.25M) bf16 [128][1024]
//
// R22 design (from R15-R21 counters):
//  - k_attn: reverted to R15 structure (measured best, 99.9us). Seven
//    scheduling variants all landed 100-106us at the fixed 2 blocks/CU
//    operating point — structural floor, stop micro-scheduling.
//  - LDS granule model (R16/R18/R21): alloc rounds to power-of-2 granule;
//    <=32KB -> 4+ blk/CU, 64KB -> 2 blk/CU, 128KB -> 1 blk/CU.
//    k_qkvf was 69,632B -> 1 blk/CU (R16-proven catastrophic). Now unpadded
//    XOR-swizzled 2x32KB = 64KB -> 2 blk/CU.
//  - k_proj: BM 64->32, grid 512 -> 2 blk/CU.
//  - k_ln + 2x k_cvt fused into one k_prep launch (6 -> 4 dispatches).

__device__ __forceinline__ unsigned short f2bf(float f) {
    unsigned u = __builtin_bit_cast(unsigned, f);
    u = (u + 0x7fffu + ((u >> 16) & 1u)) >> 16;
    return (unsigned short)u;
}
__device__ __forceinline__ float bf2f(unsigned short h) {
    unsigned u = ((unsigned)h) << 16;
    return __builtin_bit_cast(float, u);
}
__device__ __forceinline__ unsigned pk2(float a, float b) {
    return (unsigned)f2bf(a) | ((unsigned)f2bf(b) << 16);
}
// packed RNE fp32x4 -> bf16x4 via v_cvt_pk_bf16_f32 (HIP API); memcpy for the
// bit move because __hip_bfloat162 is not trivially copyable (R14 lesson).
__device__ __forceinline__ short4v pack4(const float* e) {
    __hip_bfloat162 h0 = __float22bfloat162_rn(make_float2(e[0], e[1]));
    __hip_bfloat162 h1 = __float22bfloat162_rn(make_float2(e[2], e[3]));
    uint2 u;
    __builtin_memcpy(&u.x, &h0, 4);
    __builtin_memcpy(&u.y, &h1, 4);
    return __builtin_bit_cast(short4v, u);
}

// ---------------------------------------------------------------------------
// K0: fused prep — LN (blocks 0..2047), w_qkv cvt (2048..2239),
// w_out cvt (2240..2303). One launch instead of three.
// ---------------------------------------------------------------------------
__global__ __launch_bounds__(256) void k_prep(
    const float* __restrict__ x, const float* __restrict__ g,
    const float* __restrict__ be, const float* __restrict__ w_qkv,
    const float* __restrict__ w_out, unsigned short* __restrict__ xnb,
    unsigned short* __restrict__ wqb, unsigned short* __restrict__ wob)
{
    const int bid = blockIdx.x;
    if (bid < 2048) {
        const int w = threadIdx.x >> 6, l = threadIdx.x & 63;
        const int row = bid * 4 + w;
        float2 v = *(const float2*)(x + (size_t)row * 128 + l * 2);
        float s = v.x + v.y, s2 = v.x * v.x + v.y * v.y;
#pragma unroll
        for (int off = 1; off < 64; off <<= 1) {
            s  += __shfl_xor(s, off);
            s2 += __shfl_xor(s2, off);
        }
        float mu = s * (1.f / 128.f);
        float var = s2 * (1.f / 128.f) - mu * mu;
        float rs = rsqrtf(var + EPS_);
        float2 gg = *(const float2*)(g + l * 2);
        float2 bb = *(const float2*)(be + l * 2);
        float ox = (v.x - mu) * rs * gg.x + bb.x;
        float oy = (v.y - mu) * rs * gg.y + bb.y;
        *(unsigned*)(xnb + (size_t)row * 128 + l * 2) = pk2(ox, oy);
    } else if (bid < 2240) {
        size_t i = ((size_t)(bid - 2048) * 256 + threadIdx.x) * 8;
        float4 f0 = *(const float4*)(w_qkv + i), f1 = *(const float4*)(w_qkv + i + 4);
        uint4 u = { pk2(f0.x, f0.y), pk2(f0.z, f0.w), pk2(f1.x, f1.y), pk2(f1.z, f1.w) };
        *(uint4*)(wqb + i) = u;
    } else {
        size_t i = ((size_t)(bid - 2240) * 256 + threadIdx.x) * 8;
        float4 f0 = *(const float4*)(w_out + i), f1 = *(const float4*)(w_out + i + 4);
        uint4 u = { pk2(f0.x, f0.y), pk2(f0.z, f0.w), pk2(f1.x, f1.y), pk2(f1.z, f1.w) };
        *(uint4*)(wob + i) = u;
    }
}

// ---------------------------------------------------------------------------
// K1: fused QKV GEMM + rope + scatter. M=128 x N=128, K=128 one-shot.
// Grid (64, 24). R22: UNPADDED XOR-swizzled LDS (2x32KB = 64KB -> 2 blk/CU).
// Element layout: lX[r][(chunk ^ (r&7))*8 + within], chunk = col>>3.
// ---------------------------------------------------------------------------
__global__ __launch_bounds__(256) void k_qkvf(
    const unsigned short* __restrict__ xnb, const unsigned short* __restrict__ wb,
    unsigned short* __restrict__ Q, unsigned short* __restrict__ K,
    unsigned short* __restrict__ Vt)
{
    __shared__ unsigned short lA[128 * 128];
    __shared__ unsigned short lB[128 * 128];
    const int t = threadIdx.x;
    const int wv = t >> 6, l = t & 63;
    const int lm = l & 15, quad = l >> 4;
    const int row0 = blockIdx.x * 128;
    const int by   = blockIdx.y;
    const int e0   = by * 128;

#pragma unroll
    for (int i = 0; i < 8; ++i) {
        int c = t + 256 * i;  int r = c >> 4, c8 = c & 15;
        int sc = (c8 ^ (r & 7)) * 8;
        *(uint4*)&lA[r * 128 + sc] =
            *(const uint4*)(xnb + (size_t)(row0 + r) * 128 + c8 * 8);
        *(uint4*)&lB[r * 128 + sc] =
            *(const uint4*)(wb + (size_t)(e0 + r) * 128 + c8 * 8);
    }
    __syncthreads();

    short8 af[2][4];
#pragma unroll
    for (int mt = 0; mt < 2; ++mt)
#pragma unroll
        for (int ks = 0; ks < 4; ++ks) {
            int r = wv * 32 + mt * 16 + lm;
            af[mt][ks] = *(short8*)&lA[r * 128 + (((ks * 4 + quad) ^ (r & 7)) << 3)];
        }

    f32x4 acc[2][8];
#pragma unroll
    for (int mt = 0; mt < 2; ++mt)
#pragma unroll
        for (int ct = 0; ct < 8; ++ct) acc[mt][ct] = (f32x4){0.f, 0.f, 0.f, 0.f};
#pragma unroll
    for (int ks = 0; ks < 4; ++ks) {
#pragma unroll
        for (int ct = 0; ct < 8; ++ct) {
            int r = ct * 16 + lm;
            short8 b = *(short8*)&lB[r * 128 + (((ks * 4 + quad) ^ (r & 7)) << 3)];
            acc[0][ct] = __builtin_amdgcn_mfma_f32_16x16x32_bf16(af[0][ks], b, acc[0][ct], 0, 0, 0);
            acc[1][ct] = __builtin_amdgcn_mfma_f32_16x16x32_bf16(af[1][ks], b, acc[1][ct], 0, 0, 0);
        }
    }
    __syncthreads();

    const int b  = row0 >> 11;           // batch
    const int n0 = row0 & (N_ - 1);      // n within batch (block-uniform)
    const int h  = by & 7;
    const int bh = b * 8 + h;

    if (by < 16) {
        // ---- Q or K: stage row-major (swizzled), rope, scatter ----
#pragma unroll
        for (int mt = 0; mt < 2; ++mt)
#pragma unroll
            for (int ct = 0; ct < 8; ++ct)
#pragma unroll
                for (int r = 0; r < 4; ++r) {
                    int row = wv * 32 + mt * 16 + quad * 4 + r;
                    int chunk = ct * 2 + (lm >> 3);
                    lA[row * 128 + ((chunk ^ (row & 7)) << 3) + (lm & 7)] =
                        f2bf(acc[mt][ct][r]);
                }
        __syncthreads();

        const int r_loc = t >> 1, half = t & 1;
        const int n = n0 + r_loc;
        unsigned short* dst = (by < 8 ? Q : K) +
            ((size_t)bh * N_ + n) * HEAD_ + half * 64;
        const bool dorope = (n != N_ - 1);
#pragma unroll
        for (int j = 0; j < 8; ++j) {
            short8 vv = *(short8*)&lA[r_loc * 128 + (((half * 8 + j) ^ (r_loc & 7)) << 3)];
            if (dorope) {
                unsigned short* pv = (unsigned short*)&vv;
#pragma unroll
                for (int p = 0; p < 4; ++p) {
                    int i0 = half * 32 + j * 4 + p;
                    float invf = exp2f(-(float)i0 * ROPE_C);
                    float th = (float)n * invf;
                    float cs = __cosf(th), sn = __sinf(th);
                    float e = bf2f(pv[2 * p]), o = bf2f(pv[2 * p + 1]);
                    pv[2 * p]     = f2bf(e * cs - o * sn);
                    pv[2 * p + 1] = f2bf(o * cs + e * sn);
                }
            }
            *(short8*)(dst + j * 8) = vv;
        }
    } else {
        // ---- V: stage transposed + permuted (swizzled), linear copy ----
        // local n = wv*32 + mt*16 + quad*4 + r  ->  n' = wv*32 + quad*8 + mt*4 + r
#pragma unroll
        for (int mt = 0; mt < 2; ++mt)
#pragma unroll
            for (int ct = 0; ct < 8; ++ct)
#pragma unroll
                for (int r = 0; r < 4; ++r) {
                    int row = ct * 16 + lm;            // d
                    int chunk = wv * 4 + quad;         // n' chunk
                    lA[row * 128 + ((chunk ^ (row & 7)) << 3) + mt * 4 + r] =
                        f2bf(acc[mt][ct][r]);
                }
        __syncthreads();

        const int d = t >> 1, half = t & 1;
        unsigned short* dst = Vt + ((size_t)bh * HEAD_ + d) * N_ + n0 + half * 64;
#pragma unroll
        for (int j = 0; j < 8; ++j)
            *(short8*)(dst + j * 8) =
                *(short8*)&lA[d * 128 + (((half * 8 + j) ^ (d & 7)) << 3)];
    }
}

// ---------------------------------------------------------------------------
// K3: flash attention — exact R15 structure (measured best: 99.9us).
// Single buffer, 2 barriers/jt, reg staging, padded LDS (34,816B -> 2 blk/CU).
// ---------------------------------------------------------------------------
__global__ __launch_bounds__(256) void k_attn(
    const unsigned short* __restrict__ Q, const unsigned short* __restrict__ K,
    const unsigned short* __restrict__ Vt, unsigned short* __restrict__ Ob)
{
    __shared__ unsigned short lK[64 * 136];
    __shared__ unsigned short lV[128 * 68];

    const int t = threadIdx.x;
    const int w = t >> 6, l = t & 63;
    const int lm = l & 15, quad = l >> 4;
    const int bid = blockIdx.x;
    const int bh = bid & 31;
    const int qt = bid >> 5;          // 0..15
    const int n0 = qt * 128;
    const unsigned short* Qb = Q  + (size_t)bh * N_ * HEAD_;
    const unsigned short* Kb = K  + (size_t)bh * N_ * HEAD_;
    const unsigned short* Vb = Vt + (size_t)bh * N_ * HEAD_;

    short8 aq[2][4];
#pragma unroll
    for (int tt = 0; tt < 2; ++tt) {
        const unsigned short* qp =
            Qb + ((size_t)(n0 + tt * 64 + w * 16 + lm)) * 128 + quad * 8;
#pragma unroll
        for (int ks = 0; ks < 4; ++ks)
            aq[tt][ks] = *(const short8*)(qp + ks * 32);
    }

    f32x4 Oa[2][8];
#pragma unroll
    for (int tt = 0; tt < 2; ++tt)
#pragma unroll
        for (int i = 0; i < 8; ++i) Oa[tt][i] = (f32x4){0.f, 0.f, 0.f, 0.f};
    float ps0 = 0.f, ps1 = 0.f;      // per-lane partials for row q = lm
    const float C1 = SCALE_ * 1.44269504f;
    const float C0 = -23.08312f;     // -16*log2(e); const shift is exact

    short8 kr[4], vr[4];
#pragma unroll
    for (int i = 0; i < 4; ++i) {
        int c = t + 256 * i;
        kr[i] = *(const short8*)(Kb + ((size_t)(c >> 4)) * 128 + (c & 15) * 8);
        vr[i] = *(const short8*)(Vb + (size_t)(c >> 3) * N_ + (c & 7) * 8);
    }

    for (int jt = 0; jt < 32; ++jt) {
        __syncthreads();
#pragma unroll
        for (int i = 0; i < 4; ++i) {
            int c = t + 256 * i;
            *(short8*)&lK[(c >> 4) * 136 + (c & 15) * 8] = kr[i];
            *(short8*)&lV[(c >> 3) * 68  + (c & 7)  * 8] = vr[i];
        }
        __syncthreads();
        if (jt < 31) {
#pragma unroll
            for (int i = 0; i < 4; ++i) {
                int c = t + 256 * i;
                kr[i] = *(const short8*)(Kb + ((size_t)((jt + 1) * 64 + (c >> 4))) * 128 + (c & 15) * 8);
                vr[i] = *(const short8*)(Vb + (size_t)(c >> 3) * N_ + (jt + 1) * 64 + (c & 7) * 8);
            }
        }

        short4v pf0[4], pf1[4];
#pragma unroll
        for (int nb = 0; nb < 4; ++nb) {
            f32x4 st0 = (f32x4){0.f, 0.f, 0.f, 0.f};
            f32x4 st1 = (f32x4){0.f, 0.f, 0.f, 0.f};
#pragma unroll
            for (int ks = 0; ks < 4; ++ks) {
                short8 kf = *(short8*)&lK[(nb * 16 + lm) * 136 + ks * 32 + quad * 8];
                st0 = __builtin_amdgcn_mfma_f32_16x16x32_bf16(kf, aq[0][ks], st0, 0, 0, 0);
                st1 = __builtin_amdgcn_mfma_f32_16x16x32_bf16(kf, aq[1][ks], st1, 0, 0, 0);
            }
            float e0[4], e1[4];
#pragma unroll
            for (int r = 0; r < 4; ++r) {
                e0[r] = exp2f(st0[r] * C1 + C0);
                e1[r] = exp2f(st1[r] * C1 + C0);
                ps0 += e0[r];  ps1 += e1[r];
            }
            pf0[nb] = pack4(e0);
            pf1[nb] = pack4(e1);
        }

#pragma unroll
        for (int c2 = 0; c2 < 2; ++c2) {
            short8 ap0 = __builtin_shufflevector(pf0[2 * c2], pf0[2 * c2 + 1],
                                                 0, 1, 2, 3, 4, 5, 6, 7);
            short8 ap1 = __builtin_shufflevector(pf1[2 * c2], pf1[2 * c2 + 1],
                                                 0, 1, 2, 3, 4, 5, 6, 7);
#pragma unroll
            for (int nb8 = 0; nb8 < 8; ++nb8) {
                short8 bv = *(short8*)&lV[(nb8 * 16 + lm) * 68 + c2 * 32 + quad * 8];
                Oa[0][nb8] = __builtin_amdgcn_mfma_f32_16x16x32_bf16(ap0, bv, Oa[0][nb8], 0, 0, 0);
                Oa[1][nb8] = __builtin_amdgcn_mfma_f32_16x16x32_bf16(ap1, bv, Oa[1][nb8], 0, 0, 0);
            }
        }
    }

    ps0 += __shfl_xor(ps0, 16);  ps0 += __shfl_xor(ps0, 32);
    ps1 += __shfl_xor(ps1, 16);  ps1 += __shfl_xor(ps1, 32);

    const int b = bh >> 3, h = bh & 7;
#pragma unroll
    for (int tt = 0; tt < 2; ++tt)
#pragma unroll
        for (int r = 0; r < 4; ++r) {
            float lsum = __shfl(tt == 0 ? ps0 : ps1, (l & 48) | (quad * 4 + r));
            float il = 1.f / lsum;
            int n = n0 + tt * 64 + w * 16 + quad * 4 + r;
            unsigned short* op = Ob + ((size_t)b * N_ + n) * INNER_ + h * HEAD_ + lm;
#pragma unroll
            for (int nb8 = 0; nb8 < 8; ++nb8)
                op[nb8 * 16] = f2bf(Oa[tt][nb8][r] * il);
        }
}

// ---------------------------------------------------------------------------
// K4: output projection. R22: BM=32 (grid (256,2) = 512 blocks -> 2 blk/CU).
// Per block: 32x64 out tile, K=1024. Wave wv: row tile rt=wv&1, col half
// ch=wv>>1, 2 MFMA tiles. lCf aliases lA (26KB total LDS -> 32KB granule).
// ---------------------------------------------------------------------------
__global__ __launch_bounds__(256) void k_proj(
    const unsigned short* __restrict__ Ob, const unsigned short* __restrict__ wob,
    const float* __restrict__ bias, float* __restrict__ out)
{
    __shared__ unsigned short lA[32 * 136];
    __shared__ unsigned short lB[64 * 136];
    float* lCf = (float*)lA;                 // 32*68 floats = 8704B = sizeof lA
    const int t = threadIdx.x;
    const int wv = t >> 6, l = t & 63;
    const int lm = l & 15, quad = l >> 4;
    const int rt = wv & 1, ch = wv >> 1;
    const int row0 = blockIdx.x * 32;
    const int e0   = blockIdx.y * 64;

    f32x4 acc[2];
#pragma unroll
    for (int ct = 0; ct < 2; ++ct) acc[ct] = (f32x4){0.f, 0.f, 0.f, 0.f};

    for (int kt = 0; kt < 8; ++kt) {
        __syncthreads();
#pragma unroll
        for (int i = 0; i < 2; ++i) {
            int c = t + 256 * i;  int r = c >> 4, c8 = c & 15;
            *(uint4*)&lA[r * 136 + c8 * 8] =
                *(const uint4*)(Ob + (size_t)(row0 + r) * 1024 + kt * 128 + c8 * 8);
        }
#pragma unroll
        for (int i = 0; i < 4; ++i) {
            int c = t + 256 * i;  int r = c >> 4, c8 = c & 15;
            *(uint4*)&lB[r * 136 + c8 * 8] =
                *(const uint4*)(wob + (size_t)(e0 + r) * 1024 + kt * 128 + c8 * 8);
        }
        __syncthreads();
        short8 a_[4];
#pragma unroll
        for (int ks = 0; ks < 4; ++ks)
            a_[ks] = *(short8*)&lA[(rt * 16 + lm) * 136 + ks * 32 + quad * 8];
#pragma unroll
        for (int ks = 0; ks < 4; ++ks)
#pragma unroll
            for (int ct = 0; ct < 2; ++ct) {
                short8 b = *(short8*)&lB[(ch * 32 + ct * 16 + lm) * 136 + ks * 32 + quad * 8];
                acc[ct] = __builtin_amdgcn_mfma_f32_16x16x32_bf16(a_[ks], b, acc[ct], 0, 0, 0);
            }
    }
    __syncthreads();
#pragma unroll
    for (int ct = 0; ct < 2; ++ct)
#pragma unroll
        for (int r = 0; r < 4; ++r)
            lCf[(rt * 16 + quad * 4 + r) * 68 + ch * 32 + ct * 16 + lm] = acc[ct][r];
    __syncthreads();
#pragma unroll
    for (int i = 0; i < 2; ++i) {
        int c = t + 256 * i;  int r = c >> 4, c4 = c & 15;
        float4 v = *(float4*)&lCf[r * 68 + c4 * 4];
        float4 b4 = *(const float4*)(bias + e0 + c4 * 4);
        v.x += b4.x; v.y += b4.y; v.z += b4.z; v.w += b4.w;
        *(float4*)(out + (size_t)(row0 + r) * 128 + e0 + c4 * 4) = v;
    }
}

// ---------------------------------------------------------------------------
extern "C" void kernel_launch(void* const* d_in, const int* in_sizes, int n_in,
                              void* d_out, int out_size, void* d_ws, size_t ws_size,
                              hipStream_t stream) {
    const float* x      = (const float*)d_in[0];
    const float* gamma  = (const float*)d_in[1];
    const float* beta   = (const float*)d_in[2];
    const float* w_qkv  = (const float*)d_in[3];
    const float* w_out  = (const float*)d_in[4];
    const float* b_out  = (const float*)d_in[5];
    float* out = (float*)d_out;
    char* wsb = (char*)d_ws;
    unsigned short* Q    = (unsigned short*)(wsb);
    unsigned short* K    = (unsigned short*)(wsb + (16ull << 20));
    unsigned short* Vt   = (unsigned short*)(wsb + (32ull << 20));
    unsigned short* Ob   = (unsigned short*)(wsb + (48ull << 20));
    unsigned short* xnb  = (unsigned short*)(wsb + (96ull << 20));
    unsigned short* wqb  = (unsigned short*)(wsb + (98ull << 20));
    unsigned short* wob  = (unsigned short*)(wsb + (99ull << 20));

    k_prep <<<dim3(2304),    256, 0, stream>>>(x, gamma, beta, w_qkv, w_out,
                                               xnb, wqb, wob);
    k_qkvf <<<dim3(64, 24),  256, 0, stream>>>(xnb, wqb, Q, K, Vt);
    k_attn <<<dim3(512),     256, 0, stream>>>(Q, K, Vt, Ob);
    k_proj <<<dim3(256, 2),  256, 0, stream>>>(Ob, wob, b_out, out);
}